// Round 12
// baseline (394.472 us; speedup 1.0000x reference)
//
#include <hip/hip_runtime.h>
#include <math.h>

#define NTOT  16384
#define NNODE 1024

typedef unsigned short u16;
typedef unsigned short u16x8 __attribute__((ext_vector_type(8)));
typedef short s16x8 __attribute__((ext_vector_type(8)));
typedef float f32x4 __attribute__((ext_vector_type(4)));

static __device__ __forceinline__ float b2f(u16 u) {
  return __uint_as_float(((unsigned)u) << 16);
}
static __device__ __forceinline__ u16 f2b(float f) {
  unsigned x = __float_as_uint(f);
  return (u16)((x + 0x7FFFu + ((x >> 16) & 1u)) >> 16);
}

// async global->LDS, 16B per lane; LDS dest = wave-uniform base + lane*16
typedef __attribute__((address_space(1))) const void gvoid;
typedef __attribute__((address_space(3))) void lvoid;
static __device__ __forceinline__ void gload16(const void* g, void* lds) {
  __builtin_amdgcn_global_load_lds((gvoid*)g, (lvoid*)lds, 16, 0, 0);
}

// ---------------- embedding: h = obs @ Wemb + b (K=32, N=128) ----------------
__global__ __launch_bounds__(64) void emb_k(const float* __restrict__ obs,
    const float* __restrict__ W, const float* __restrict__ b,
    float* __restrict__ h, float* __restrict__ hh, u16* __restrict__ h_bf)
{
  int n = blockIdx.x, l = threadIdx.x;
  __shared__ float ob[32];
  if (l < 32) ob[l] = obs[n * 32 + l];
  __syncthreads();
  float a0 = b[l], a1 = b[64 + l];
  #pragma unroll
  for (int k = 0; k < 32; ++k) {
    float o = ob[k];
    a0 = fmaf(o, W[k * 128 + l], a0);
    a1 = fmaf(o, W[k * 128 + 64 + l], a1);
  }
  size_t base = (size_t)n * 128;
  h[base + l] = a0;  h[base + 64 + l] = a1;
  hh[base + l] = a0; hh[base + 64 + l] = a1;
  h_bf[base + l] = f2b(a0); h_bf[base + 64 + l] = f2b(a1);
}

// ---------------- CSR build ----------------
__global__ void hist_k(const int* __restrict__ ei, int E0, int* __restrict__ deg)
{
  int i = blockIdx.x * blockDim.x + threadIdx.x;
  int ET = E0 + NTOT;
  if (i < ET) {
    int d = (i < E0) ? ei[E0 + i] : (i - E0);
    atomicAdd(&deg[d], 1);
  }
}

__global__ __launch_bounds__(256) void scan_k(const int* __restrict__ deg,
    int* __restrict__ off, int* __restrict__ cursor)
{
  int t = threadIdx.x, lane = t & 63, wid = t >> 6;
  int base = t * 64;
  int sum = 0;
  for (int i = 0; i < 64; ++i) sum += deg[base + i];
  int inc = sum;
  #pragma unroll
  for (int d = 1; d < 64; d <<= 1) {
    int u = __shfl_up(inc, d);
    if (lane >= d) inc += u;
  }
  __shared__ int wt[4];
  if (lane == 63) wt[wid] = inc;
  __syncthreads();
  int woff = 0;
  for (int i = 0; i < wid; ++i) woff += wt[i];
  int run = woff + inc - sum;      // exclusive prefix of this thread's 64-chunk
  for (int i = 0; i < 64; ++i) {
    off[base + i] = run; cursor[base + i] = run;
    run += deg[base + i];
  }
  if (t == 255) off[NTOT] = run;
}

__global__ void scat_k(const int* __restrict__ ei, int E0,
    int* __restrict__ cursor, int* __restrict__ csr_src)
{
  int i = blockIdx.x * blockDim.x + threadIdx.x;
  int ET = E0 + NTOT;
  if (i < ET) {
    int s, d;
    if (i < E0) { s = ei[i]; d = ei[E0 + i]; } else { s = d = i - E0; }
    int pos = atomicAdd(&cursor[d], 1);
    csr_src[pos] = s;
  }
}

// ---------------- degree-sorted dst permutation (per graph, counting sort) --------
// waves process consecutive sorted slots -> paired dsts have ~equal degree
__global__ void dhist_k(const int* __restrict__ deg, int* __restrict__ dh)
{
  int n = blockIdx.x * 256 + threadIdx.x;
  if (n < NTOT) {
    int d = deg[n]; d = d < 63 ? d : 63;
    atomicAdd(&dh[(n >> 10) * 64 + d], 1);
  }
}
__global__ void dscan_k(const int* __restrict__ dh, int* __restrict__ dcur)
{
  int g = threadIdx.x;
  if (g < 16) {
    int run = 0;
    for (int d = 0; d < 64; ++d) { dcur[g * 64 + d] = run; run += dh[g * 64 + d]; }
  }
}
__global__ void dscat_k(const int* __restrict__ deg, int* __restrict__ dcur,
                        int* __restrict__ perm)
{
  int n = blockIdx.x * 256 + threadIdx.x;
  if (n < NTOT) {
    int gph = n >> 10;
    int d = deg[n]; d = d < 63 ? d : 63;
    int pos = atomicAdd(&dcur[gph * 64 + d], 1);
    perm[gph * 1024 + pos] = n;
  }
}

// ---------------- all weight transposes + bf16 quantize in ONE kernel ----------------
// out layout: [lWT 262144][hWT 262144][W1T 65536][W2T 65536]
__global__ void wqall_k(const float* __restrict__ lWl, const float* __restrict__ lWr,
                        const float* __restrict__ hWl, const float* __restrict__ hWr,
                        const float* __restrict__ W1, const float* __restrict__ W2,
                        u16* __restrict__ out)
{
  int idx = blockIdx.x * 256 + threadIdx.x;
  if (idx >= 655360) return;
  float v;
  if (idx < 524288) {
    const float* Wl = idx < 262144 ? lWl : hWl;
    const float* Wr = idx < 262144 ? lWr : hWr;
    int r2 = idx & 262143;
    int m = r2 >> 17, r = r2 & 131071;
    int n = r >> 7, k = r & 127;
    const float* W = (n < 512) ? Wl : Wr;
    v = W[(size_t)m * 65536 + (size_t)k * 512 + (n & 511)];
  } else if (idx < 589824) {
    int i = idx - 524288;
    int n = i >> 7, k = i & 127;
    v = W1[k * 512 + n];
  } else {
    int i = idx - 589824;
    int n = i >> 9, k = i & 511;
    v = W2[k * 128 + n];
  }
  out[idx] = f2b(v);
}

// ---------------- bf16 MFMA GEMM (BM=128): C = A[M,K] @ Bt[N,K]^T + bias ----------------
// staging via global_load_lds; LDS linear, inverse-XOR swizzle on global src addr.
// rswz: remap row-block so graph rows land on the XCD that gat will read them from
// (requires gridDim.x == 128; bx' = (bx&7)*16 + bx>>3 -> graph(bx') >> 1 == bx&7)
__global__ __launch_bounds__(256) void gemm_bf16(
    const u16* __restrict__ A, const u16* __restrict__ Bt,
    const float* __restrict__ bias0, const float* __restrict__ bias1,
    float* __restrict__ Cf, u16* __restrict__ Cb0, u16* __restrict__ Cb1,
    const float* __restrict__ res,
    int M, int K, int N, int Nsplit, int act, int rswz)
{
  __shared__ u16 Al[128][128];
  __shared__ u16 Bl[128][128];
  const int tid = threadIdx.x;
  int bx = blockIdx.x;
  if (rswz) bx = (bx & 7) * 16 + (bx >> 3);
  const int bm = bx * 128, bn = blockIdx.y * 128;
  const int w = tid >> 6, l = tid & 63;
  const int fr = l & 15;
  const int kg = l >> 4;
  const int lrow = l >> 4, gsl = l & 15;   // staging: 4 rows x 16 granules per instr

  f32x4 acc[2][8];
  #pragma unroll
  for (int a = 0; a < 2; ++a)
    #pragma unroll
    for (int b = 0; b < 8; ++b)
      acc[a][b] = (f32x4){0.f, 0.f, 0.f, 0.f};

  for (int k0 = 0; k0 < K; k0 += 128) {
    __syncthreads();
    #pragma unroll
    for (int j = 0; j < 8; ++j) {
      int row = w * 32 + j * 4 + lrow;
      int gsrc = gsl ^ (row & 7);
      gload16(A + (size_t)(bm + row) * K + k0 + gsrc * 8, &Al[w * 32 + j * 4][0]);
    }
    #pragma unroll
    for (int j = 0; j < 8; ++j) {
      int row = w * 32 + j * 4 + lrow;
      int gsrc = gsl ^ (row & 7);
      gload16(Bt + (size_t)(bn + row) * K + k0 + gsrc * 8, &Bl[w * 32 + j * 4][0]);
    }
    __syncthreads();
    #pragma unroll
    for (int ks = 0; ks < 4; ++ks) {
      const int g = (ks << 2) + kg;
      const int ar0 = w * 32 + fr, ar1 = ar0 + 16;
      s16x8 a0 = *(const s16x8*)&Al[ar0][(g ^ (ar0 & 7)) << 3];
      s16x8 a1 = *(const s16x8*)&Al[ar1][(g ^ (ar1 & 7)) << 3];
      #pragma unroll
      for (int nr = 0; nr < 8; ++nr) {
        const int br = nr * 16 + fr;
        s16x8 bb = *(const s16x8*)&Bl[br][(g ^ (br & 7)) << 3];
        acc[0][nr] = __builtin_amdgcn_mfma_f32_16x16x32_bf16(a0, bb, acc[0][nr], 0, 0, 0);
        acc[1][nr] = __builtin_amdgcn_mfma_f32_16x16x32_bf16(a1, bb, acc[1][nr], 0, 0, 0);
      }
    }
  }

  #pragma unroll
  for (int mr = 0; mr < 2; ++mr) {
    const int row0 = bm + w * 32 + mr * 16 + (kg << 2);
    #pragma unroll
    for (int nr = 0; nr < 8; ++nr) {
      const int col = bn + nr * 16 + fr;
      const int half = (col >= Nsplit);
      const int c2 = half ? col - Nsplit : col;
      const int str = half ? (N - Nsplit) : Nsplit;
      const float bb = half ? bias1[c2] : bias0[c2];
      u16* cb = half ? Cb1 : Cb0;
      #pragma unroll
      for (int j = 0; j < 4; ++j) {
        float v = acc[mr][nr][j] + bb;
        if (act) v = tanhf(v);
        size_t o = (size_t)(row0 + j) * str + c2;
        if (res) v += res[o];
        if (Cf) Cf[o] = v;
        if (cb) cb[o] = f2b(v);
      }
    }
  }
}

// ---------------- bf16 MFMA GEMM (BM=64) — for skinny/tall shapes ----------------
__global__ __launch_bounds__(256) void gemm64_bf16(
    const u16* __restrict__ A, const u16* __restrict__ Bt,
    const float* __restrict__ bias0, const float* __restrict__ bias1,
    float* __restrict__ Cf, u16* __restrict__ Cb0, u16* __restrict__ Cb1,
    const float* __restrict__ res,
    int M, int K, int N, int Nsplit, int act)
{
  __shared__ u16 Al[64][128];
  __shared__ u16 Bl[128][128];
  const int tid = threadIdx.x;
  const int bm = blockIdx.x * 64, bn = blockIdx.y * 128;
  const int w = tid >> 6, l = tid & 63;
  const int fr = l & 15;
  const int kg = l >> 4;
  const int lrow = l >> 4, gsl = l & 15;

  f32x4 acc[8];
  #pragma unroll
  for (int b = 0; b < 8; ++b) acc[b] = (f32x4){0.f, 0.f, 0.f, 0.f};

  for (int k0 = 0; k0 < K; k0 += 128) {
    __syncthreads();
    #pragma unroll
    for (int j = 0; j < 4; ++j) {
      int row = w * 16 + j * 4 + lrow;
      int gsrc = gsl ^ (row & 7);
      gload16(A + (size_t)(bm + row) * K + k0 + gsrc * 8, &Al[w * 16 + j * 4][0]);
    }
    #pragma unroll
    for (int j = 0; j < 8; ++j) {
      int row = w * 32 + j * 4 + lrow;
      int gsrc = gsl ^ (row & 7);
      gload16(Bt + (size_t)(bn + row) * K + k0 + gsrc * 8, &Bl[w * 32 + j * 4][0]);
    }
    __syncthreads();
    #pragma unroll
    for (int ks = 0; ks < 4; ++ks) {
      const int g = (ks << 2) + kg;
      const int ar0 = w * 16 + fr;
      s16x8 a0 = *(const s16x8*)&Al[ar0][(g ^ (ar0 & 7)) << 3];
      #pragma unroll
      for (int nr = 0; nr < 8; ++nr) {
        const int br = nr * 16 + fr;
        s16x8 bb = *(const s16x8*)&Bl[br][(g ^ (br & 7)) << 3];
        acc[nr] = __builtin_amdgcn_mfma_f32_16x16x32_bf16(a0, bb, acc[nr], 0, 0, 0);
      }
    }
  }

  const int row0 = bm + w * 16 + (kg << 2);
  #pragma unroll
  for (int nr = 0; nr < 8; ++nr) {
    const int col = bn + nr * 16 + fr;
    const int half = (col >= Nsplit);
    const int c2 = half ? col - Nsplit : col;
    const int str = half ? (N - Nsplit) : Nsplit;
    const float bb = half ? bias1[c2] : bias0[c2];
    u16* cb = half ? Cb1 : Cb0;
    #pragma unroll
    for (int j = 0; j < 4; ++j) {
      float v = acc[nr][j] + bb;
      if (act) v = tanhf(v);
      size_t o = (size_t)(row0 + j) * str + c2;
      if (res) v += res[o];
      if (Cf) Cf[o] = v;
      if (cb) cb[o] = f2b(v);
    }
  }
}

// ---------------- GATv2 edge step (online softmax, one head per 16-lane group)
static __device__ __forceinline__ void estep(
    u16x8 vv, bool valid, u16x8 xrb, const float* attr,
    float& m, float& z, float* acc)
{
  float xv[8], part = 0.f;
  #pragma unroll
  for (int i = 0; i < 8; ++i) {
    xv[i] = b2f(vv[i]);
    float v = xv[i] + b2f(xrb[i]);
    part = fmaf(fmaxf(v, 0.2f * v), attr[i], part);   // leaky_relu
  }
  part += __shfl_xor(part, 1); part += __shfl_xor(part, 2);
  part += __shfl_xor(part, 4); part += __shfl_xor(part, 8);
  if (!valid) part = -1e30f;
  float mn = fmaxf(m, part);
  float sc = __expf(m - mn);
  float p  = __expf(part - mn);
  z = z * sc + p;
  #pragma unroll
  for (int i = 0; i < 8; ++i) acc[i] = fmaf(acc[i], sc, p * xv[i]);
  m = mn;
}

// ---------------- dual-dst fused GATv2, 4 waves/block (occupancy fix) ----------
// each wave handles 2 degree-sorted slots; 256-thread blocks pack 4x more waves/CU
__global__ __launch_bounds__(256) void gat_agg2(
    const u16* __restrict__ xl, const u16* __restrict__ xr,
    const int* __restrict__ off, const int* __restrict__ srcs,
    const int* __restrict__ perm,
    const float* __restrict__ att, const float* __restrict__ bias,
    const float* __restrict__ g, const float* __restrict__ beta,
    float* __restrict__ h, u16* __restrict__ h_bf,
    const float* __restrict__ res2, int do_silu, int swz)
{
  const int b = blockIdx.x, tid = threadIdx.x;
  const int l = tid & 63, w = tid >> 6;
  int slot0;
  if (swz) {
    // pin graphs to XCDs: XCD x serves graphs {2x,2x+1} (matches gemm rswz)
    int xcd = b & 7, i = b >> 3;            // i: 0..255 (256 blocks/XCD)
    slot0 = ((((xcd << 1) + (i >> 7)) << 10) | ((i & 127) << 3)) + (w << 1);
  } else slot0 = (b << 3) + (w << 1);
  const int dst0 = perm[slot0], dst1 = perm[slot0 + 1];

  float attr[8];
  {
    const float4 a0 = *(const float4*)(att + l * 8);
    const float4 a1 = *(const float4*)(att + l * 8 + 4);
    attr[0] = a0.x; attr[1] = a0.y; attr[2] = a0.z; attr[3] = a0.w;
    attr[4] = a1.x; attr[5] = a1.y; attr[6] = a1.z; attr[7] = a1.w;
  }
  u16x8 xrb0 = *(const u16x8*)(xr + (size_t)dst0 * 512 + l * 8);
  u16x8 xrb1 = *(const u16x8*)(xr + (size_t)dst1 * 512 + l * 8);

  const int s0 = off[dst0], n0 = off[dst0 + 1] - s0;
  const int s1 = off[dst1], n1 = off[dst1 + 1] - s1;
  const int nmax = n0 > n1 ? n0 : n1;     // degree-sorted: |n0-n1| ~ 0

  int ni0 = (n0 > 1) ? srcs[s0 + 1] : 0;
  int ni1 = (n1 > 1) ? srcs[s1 + 1] : 0;
  u16x8 v0 = *(const u16x8*)(xl + (size_t)srcs[s0] * 512 + l * 8);
  u16x8 v1 = *(const u16x8*)(xl + (size_t)srcs[s1] * 512 + l * 8);

  float m0 = -1e30f, z0 = 0.f, acc0[8] = {};
  float m1 = -1e30f, z1 = 0.f, acc1[8] = {};

  for (int e = 0; e < nmax; ++e) {
    u16x8 c0 = v0, c1 = v1;
    if (e + 1 < nmax) {
      v0 = *(const u16x8*)(xl + (size_t)ni0 * 512 + l * 8);
      v1 = *(const u16x8*)(xl + (size_t)ni1 * 512 + l * 8);
      if (e + 2 < n0) ni0 = srcs[s0 + e + 2];
      if (e + 2 < n1) ni1 = srcs[s1 + e + 2];
    }
    estep(c0, e < n0, xrb0, attr, m0, z0, acc0);
    estep(c1, e < n1, xrb1, attr, m1, z1, acc1);
  }

  const int d0 = (l & 15) * 8;
  float o0[8], o1[8];
  const float inv0 = 0.25f / z0, inv1 = 0.25f / z1;   // mean over 4 heads folded
  #pragma unroll
  for (int i = 0; i < 8; ++i) {
    float v = acc0[i] * inv0;
    v += __shfl_xor(v, 16); v += __shfl_xor(v, 32);   // sum heads
    o0[i] = v + bias[d0 + i];
    float w2 = acc1[i] * inv1;
    w2 += __shfl_xor(w2, 16); w2 += __shfl_xor(w2, 32);
    o1[i] = w2 + bias[d0 + i];
  }
  // LayerNorm over 128 dims (each 16-lane group holds a full copy)
  float sa = 0.f, sb = 0.f;
  #pragma unroll
  for (int i = 0; i < 8; ++i) { sa += o0[i]; sb += o1[i]; }
  sa += __shfl_xor(sa, 1); sa += __shfl_xor(sa, 2);
  sa += __shfl_xor(sa, 4); sa += __shfl_xor(sa, 8);
  sb += __shfl_xor(sb, 1); sb += __shfl_xor(sb, 2);
  sb += __shfl_xor(sb, 4); sb += __shfl_xor(sb, 8);
  const float mu0 = sa * (1.f / 128.f), mu1 = sb * (1.f / 128.f);
  float va = 0.f, vb = 0.f;
  #pragma unroll
  for (int i = 0; i < 8; ++i) {
    float d = o0[i] - mu0; va += d * d;
    float e = o1[i] - mu1; vb += e * e;
  }
  va += __shfl_xor(va, 1); va += __shfl_xor(va, 2);
  va += __shfl_xor(va, 4); va += __shfl_xor(va, 8);
  vb += __shfl_xor(vb, 1); vb += __shfl_xor(vb, 2);
  vb += __shfl_xor(vb, 4); vb += __shfl_xor(vb, 8);
  const float rstd0 = rsqrtf(va * (1.f / 128.f) + 1e-5f);
  const float rstd1 = rsqrtf(vb * (1.f / 128.f) + 1e-5f);

  const float* oo = (l < 16) ? o0 : o1;
  const float mu = (l < 16) ? mu0 : mu1;
  const float rstd = (l < 16) ? rstd0 : rstd1;
  const int dd = (l < 16) ? dst0 : dst1;
  if (l < 32) {
    size_t base = (size_t)dd * 128 + d0;
    float4 r0 = *(const float4*)(h + base);
    float4 r1 = *(const float4*)(h + base + 4);
    float rr[8] = {r0.x, r0.y, r0.z, r0.w, r1.x, r1.y, r1.z, r1.w};
    if (res2) {
      float4 q0 = *(const float4*)(res2 + base);
      float4 q1 = *(const float4*)(res2 + base + 4);
      rr[0] += q0.x; rr[1] += q0.y; rr[2] += q0.z; rr[3] += q0.w;
      rr[4] += q1.x; rr[5] += q1.y; rr[6] += q1.z; rr[7] += q1.w;
    }
    float out[8];
    u16x8 hb;
    #pragma unroll
    for (int i = 0; i < 8; ++i) {
      float y = (oo[i] - mu) * rstd * g[d0 + i] + beta[d0 + i];
      if (do_silu) y = y / (1.f + __expf(-y));
      out[i] = y + rr[i];
      hb[i] = f2b(out[i]);
    }
    *(float4*)(h + base) = make_float4(out[0], out[1], out[2], out[3]);
    *(float4*)(h + base + 4) = make_float4(out[4], out[5], out[6], out[7]);
    *(u16x8*)(h_bf + base) = hb;
  }
}

// ---------------- fully-connected-16 GATv2 (high level): shared row loads ----------------
__global__ __launch_bounds__(64) void gat_fc16(
    const u16* __restrict__ xl, const u16* __restrict__ xr,
    const float* __restrict__ att, const float* __restrict__ bias,
    const float* __restrict__ g, const float* __restrict__ beta,
    float* __restrict__ h, u16* __restrict__ h_bf,
    const float* __restrict__ res2, int do_silu)
{
  int b = blockIdx.x, l = threadIdx.x;
  const int dst0 = b << 2;
  const int gbase = dst0 & ~15;      // all 4 dsts share one 16-node graph

  float attr[8];
  {
    const float4 a0 = *(const float4*)(att + l * 8);
    const float4 a1 = *(const float4*)(att + l * 8 + 4);
    attr[0] = a0.x; attr[1] = a0.y; attr[2] = a0.z; attr[3] = a0.w;
    attr[4] = a1.x; attr[5] = a1.y; attr[6] = a1.z; attr[7] = a1.w;
  }
  u16x8 xrb[4];
  #pragma unroll
  for (int q = 0; q < 4; ++q)
    xrb[q] = *(const u16x8*)(xr + (size_t)(dst0 + q) * 512 + l * 8);

  float m[4] = {-1e30f, -1e30f, -1e30f, -1e30f};
  float z[4] = {0.f, 0.f, 0.f, 0.f};
  float acc[4][8] = {};
  u16x8 vcur = *(const u16x8*)(xl + (size_t)gbase * 512 + l * 8);
  for (int e = 0; e < 16; ++e) {
    u16x8 c = vcur;
    if (e < 15) vcur = *(const u16x8*)(xl + (size_t)(gbase + e + 1) * 512 + l * 8);
    estep(c, true, xrb[0], attr, m[0], z[0], acc[0]);
    estep(c, true, xrb[1], attr, m[1], z[1], acc[1]);
    estep(c, true, xrb[2], attr, m[2], z[2], acc[2]);
    estep(c, true, xrb[3], attr, m[3], z[3], acc[3]);
  }

  const int d0 = (l & 15) * 8;
  float mu[4], rs[4];
  #pragma unroll
  for (int q = 0; q < 4; ++q) {
    const float inv = 0.25f / z[q];
    #pragma unroll
    for (int i = 0; i < 8; ++i) {
      float x = acc[q][i] * inv;
      x += __shfl_xor(x, 16); x += __shfl_xor(x, 32);
      acc[q][i] = x + bias[d0 + i];
    }
    float sa = 0.f;
    #pragma unroll
    for (int i = 0; i < 8; ++i) sa += acc[q][i];
    sa += __shfl_xor(sa, 1); sa += __shfl_xor(sa, 2);
    sa += __shfl_xor(sa, 4); sa += __shfl_xor(sa, 8);
    mu[q] = sa * (1.f / 128.f);
    float va = 0.f;
    #pragma unroll
    for (int i = 0; i < 8; ++i) { float d = acc[q][i] - mu[q]; va += d * d; }
    va += __shfl_xor(va, 1); va += __shfl_xor(va, 2);
    va += __shfl_xor(va, 4); va += __shfl_xor(va, 8);
    rs[q] = rsqrtf(va * (1.f / 128.f) + 1e-5f);
  }
  float oo[8];
  #pragma unroll
  for (int i = 0; i < 8; ++i)
    oo[i] = (l < 32) ? (l < 16 ? acc[0][i] : acc[1][i])
                     : (l < 48 ? acc[2][i] : acc[3][i]);
  const float mmu = (l < 32) ? (l < 16 ? mu[0] : mu[1]) : (l < 48 ? mu[2] : mu[3]);
  const float mrs = (l < 32) ? (l < 16 ? rs[0] : rs[1]) : (l < 48 ? rs[2] : rs[3]);
  const int dd = dst0 + (l >> 4);
  size_t base = (size_t)dd * 128 + d0;
  float4 r0 = *(const float4*)(h + base);
  float4 r1 = *(const float4*)(h + base + 4);
  float rr[8] = {r0.x, r0.y, r0.z, r0.w, r1.x, r1.y, r1.z, r1.w};
  if (res2) {
    float4 q0 = *(const float4*)(res2 + base);
    float4 q1 = *(const float4*)(res2 + base + 4);
    rr[0] += q0.x; rr[1] += q0.y; rr[2] += q0.z; rr[3] += q0.w;
    rr[4] += q1.x; rr[5] += q1.y; rr[6] += q1.z; rr[7] += q1.w;
  }
  float out[8];
  u16x8 hb;
  #pragma unroll
  for (int i = 0; i < 8; ++i) {
    float y = (oo[i] - mmu) * mrs * g[d0 + i] + beta[d0 + i];
    if (do_silu) y = y / (1.f + __expf(-y));
    out[i] = y + rr[i];
    hb[i] = f2b(out[i]);
  }
  *(float4*)(h + base) = make_float4(out[0], out[1], out[2], out[3]);
  *(float4*)(h + base + 4) = make_float4(out[4], out[5], out[6], out[7]);
  *(u16x8*)(h_bf + base) = hb;
}

// ---------------- fused pooling softmax + cluster partials ----------------
#define HF_CHUNK 32
#define HF_NCH   32
__global__ __launch_bounds__(256) void poolhf_k(const float* __restrict__ h,
    const float* __restrict__ pW, const float* __restrict__ pb,
    float* __restrict__ s, float* __restrict__ part, float* __restrict__ cpart)
{
  __shared__ float hs[HF_CHUNK][128];   // 16 KB
  __shared__ float Ws[128][16];         // 8 KB
  __shared__ float ss[HF_CHUNK][16];    // 2 KB
  int b = blockIdx.x >> 5, chunk = blockIdx.x & 31;
  int n0 = b * NNODE + chunk * HF_CHUNK;
  int t = threadIdx.x;
  #pragma unroll
  for (int i = 0; i < 4; ++i) {
    int idx = t + 256 * i;              // float4 index 0..1023
    int row = idx >> 5, c4 = (idx & 31) * 4;
    *(float4*)&hs[row][c4] = *(const float4*)(h + (size_t)(n0 + row) * 128 + c4);
  }
  #pragma unroll
  for (int i = 0; i < 2; ++i) {
    int idx = t + 256 * i;              // float4 index 0..511
    *(float4*)&Ws[idx >> 2][(idx & 3) * 4] = *(const float4*)(pW + idx * 4);
  }
  __syncthreads();
  // pooling softmax: thread t -> nodes {t>>4, 16+(t>>4)}, class c = t&15
  const int c = t & 15, nA = t >> 4;
  const float bb = pb[c];
  #pragma unroll
  for (int half = 0; half < 2; ++half) {
    const int nn = nA + half * 16;
    float a = bb;
    for (int k = 0; k < 128; ++k) a = fmaf(hs[nn][k], Ws[k][c], a);
    float mx = a;
    mx = fmaxf(mx, __shfl_xor(mx, 1)); mx = fmaxf(mx, __shfl_xor(mx, 2));
    mx = fmaxf(mx, __shfl_xor(mx, 4)); mx = fmaxf(mx, __shfl_xor(mx, 8));
    float p = __expf(a - mx), sum = p;
    sum += __shfl_xor(sum, 1); sum += __shfl_xor(sum, 2);
    sum += __shfl_xor(sum, 4); sum += __shfl_xor(sum, 8);
    float sv = p / sum;
    ss[nn][c] = sv;
    s[(size_t)(n0 + nn) * 16 + c] = sv;
  }
  __syncthreads();
  // partials: thread t -> dim d = t&127, classes cg..cg+7
  const int d = t & 127, cg = (t >> 7) * 8;
  float acc[8] = {};
  for (int n = 0; n < HF_CHUNK; ++n) {
    float hv = hs[n][d];
    #pragma unroll
    for (int i = 0; i < 8; ++i) acc[i] = fmaf(ss[n][cg + i], hv, acc[i]);
  }
  float* po = part + (size_t)chunk * 32768 + (size_t)(b * 16 + cg) * 128 + d;
  #pragma unroll
  for (int i = 0; i < 8; ++i) po[i * 128] = acc[i];
  if (t < 16) {
    float cs = 0.f;
    #pragma unroll
    for (int n = 0; n < HF_CHUNK; ++n) cs += ss[n][t];
    cpart[chunk * 256 + b * 16 + t] = cs;
  }
}

// ---------------- cluster features, stage 2: reduce chunks + normalize
__global__ __launch_bounds__(256) void hfr_k(const float* __restrict__ part,
    const float* __restrict__ cpart, float* __restrict__ Hf,
    float* __restrict__ HfRes, u16* __restrict__ Hf_bf)
{
  int o = blockIdx.x * 256 + threadIdx.x;
  int bc = o >> 7;
  float a = 0.f, cnt = 0.f;
  #pragma unroll 8
  for (int ch = 0; ch < HF_NCH; ++ch) {
    a += part[(size_t)ch * 32768 + o];
    cnt += cpart[ch * 256 + bc];
  }
  float v = a / fmaxf(cnt, 1e-5f);
  Hf[o] = v; HfRes[o] = v; Hf_bf[o] = f2b(v);
}

// ---------------- unpool + residual: x = s @ Hf + hh ----------------
__global__ __launch_bounds__(64) void unpool_k(const float* __restrict__ s,
    const float* __restrict__ Hf, const float* __restrict__ hh,
    float* __restrict__ x, u16* __restrict__ x_bf)
{
  int n = blockIdx.x, l = threadIdx.x;
  int b = n >> 10;
  float a0 = 0.f, a1 = 0.f;
  #pragma unroll
  for (int c = 0; c < 16; ++c) {
    float sv = s[(size_t)n * 16 + c];
    const float* hp = Hf + (size_t)((b << 4) + c) * 128;
    a0 = fmaf(sv, hp[l], a0);
    a1 = fmaf(sv, hp[64 + l], a1);
  }
  size_t base = (size_t)n * 128;
  float v0 = a0 + hh[base + l], v1 = a1 + hh[base + 64 + l];
  x[base + l] = v0; x[base + 64 + l] = v1;
  x_bf[base + l] = f2b(v0); x_bf[base + 64 + l] = f2b(v1);
}

extern "C" void kernel_launch(void* const* d_in, const int* in_sizes, int n_in,
                              void* d_out, int out_size, void* d_ws, size_t ws_size,
                              hipStream_t stream) {
  (void)n_in; (void)out_size; (void)ws_size;
  const float* obs    = (const float*)d_in[0];
  const int*   ei     = (const int*)d_in[1];
  const float* emb_W  = (const float*)d_in[3];
  const float* emb_b  = (const float*)d_in[4];
  const float* pool_W = (const float*)d_in[5];
  const float* pool_b = (const float*)d_in[6];
  const float* mlp_W1 = (const float*)d_in[7];
  const float* mlp_b1 = (const float*)d_in[8];
  const float* mlp_W2 = (const float*)d_in[9];
  const float* mlp_b2 = (const float*)d_in[10];
  const float* lWl = (const float*)d_in[11]; const float* lbl = (const float*)d_in[12];
  const float* lWr = (const float*)d_in[13]; const float* lbr = (const float*)d_in[14];
  const float* latt = (const float*)d_in[15]; const float* lbias = (const float*)d_in[16];
  const float* lg = (const float*)d_in[17]; const float* lbeta = (const float*)d_in[18];
  const float* hWl = (const float*)d_in[19]; const float* hbl = (const float*)d_in[20];
  const float* hWr = (const float*)d_in[21]; const float* hbr = (const float*)d_in[22];
  const float* hatt = (const float*)d_in[23]; const float* hbias = (const float*)d_in[24];
  const float* hg = (const float*)d_in[25]; const float* hbeta = (const float*)d_in[26];

  const int E0 = in_sizes[1] / 2;
  const int ET = E0 + NTOT;

  char* p = (char*)d_ws;
  auto alloc = [&](size_t bytes) -> void* {
    void* q = (void*)p;
    p += (bytes + 255) & ~(size_t)255;
    return q;
  };
  float* h      = (float*)alloc((size_t)NTOT * 128 * 4);
  float* hh     = (float*)alloc((size_t)NTOT * 128 * 4);
  u16*   h_bf   = (u16*)alloc((size_t)NTOT * 128 * 2);
  u16*   xl_bf  = (u16*)alloc((size_t)NTOT * 512 * 2);
  u16*   xr_bf  = (u16*)alloc((size_t)NTOT * 512 * 2);
  u16*   x_bf   = (u16*)alloc((size_t)NTOT * 128 * 2);
  float* s      = (float*)alloc((size_t)NTOT * 16 * 4);
  float* Hf     = (float*)alloc(256 * 128 * 4);
  float* HfRes  = (float*)alloc(256 * 128 * 4);
  u16*   Hf_bf  = (u16*)alloc(256 * 128 * 2);
  u16*   hxl    = (u16*)alloc(256 * 512 * 2);
  u16*   hxr    = (u16*)alloc(256 * 512 * 2);
  float* hfPart = (float*)alloc((size_t)HF_NCH * 32768 * 4);
  float* hfCnt  = (float*)alloc((size_t)HF_NCH * 256 * 4);
  u16*   WT     = (u16*)alloc((size_t)655360 * 2);   // [lWT|hWT|W1T|W2T]
  int* deg      = (int*)alloc((size_t)NTOT * 4);
  int* off      = (int*)alloc((size_t)(NTOT + 1) * 4);
  int* cursor   = (int*)alloc((size_t)NTOT * 4);
  int* csr      = (int*)alloc((size_t)ET * 4);
  int* perm     = (int*)alloc((size_t)NTOT * 4);
  int* dh       = (int*)alloc(16 * 64 * 4);
  int* dcur     = (int*)alloc(16 * 64 * 4);
  u16* lWT = WT;
  u16* hWT = WT + 262144;
  u16* W1T = WT + 524288;
  u16* W2T = WT + 589824;
  u16* t_bf = xl_bf;   // alias: xl_bf is free by MLP time

  wqall_k<<<2560, 256, 0, stream>>>(lWl, lWr, hWl, hWr, mlp_W1, mlp_W2, WT);

  hipMemsetAsync(deg, 0, (size_t)NTOT * 4, stream);
  hipMemsetAsync(dh, 0, 16 * 64 * 4, stream);
  emb_k<<<NTOT, 64, 0, stream>>>(obs, emb_W, emb_b, h, hh, h_bf);
  hist_k<<<(ET + 255) / 256, 256, 0, stream>>>(ei, E0, deg);
  scan_k<<<1, 256, 0, stream>>>(deg, off, cursor);
  scat_k<<<(ET + 255) / 256, 256, 0, stream>>>(ei, E0, cursor, csr);
  dhist_k<<<NTOT / 256, 256, 0, stream>>>(deg, dh);
  dscan_k<<<1, 64, 0, stream>>>(dh, dcur);
  dscat_k<<<NTOT / 256, 256, 0, stream>>>(deg, dcur, perm);

  // low-level GAT stack (in-place on h; stack residual == hh)
  for (int j = 0; j < 2; ++j) {
    gemm_bf16<<<dim3(NTOT / 128, 8), 256, 0, stream>>>(h_bf, lWT + j * 131072,
        lbl + j * 512, lbr + j * 512, nullptr, xl_bf, xr_bf, nullptr,
        NTOT, 128, 1024, 512, 0, 1);
    gat_agg2<<<NTOT / 8, 256, 0, stream>>>(xl_bf, xr_bf, off, csr, perm,
        latt + j * 512, lbias + j * 128, lg + j * 128, lbeta + j * 128, h, h_bf,
        j == 1 ? hh : nullptr, j == 0 ? 1 : 0, 1);
  }

  poolhf_k<<<16 * HF_NCH, 256, 0, stream>>>(h, pool_W, pool_b, s, hfPart, hfCnt);
  hfr_k<<<128, 256, 0, stream>>>(hfPart, hfCnt, Hf, HfRes, Hf_bf);

  // high-level GAT stack on 256 cluster nodes (fully-connected 16-node graphs)
  for (int j = 0; j < 2; ++j) {
    gemm64_bf16<<<dim3(4, 8), 256, 0, stream>>>(Hf_bf, hWT + j * 131072,
        hbl + j * 512, hbr + j * 512, nullptr, hxl, hxr, nullptr,
        256, 128, 1024, 512, 0);
    gat_fc16<<<64, 64, 0, stream>>>(hxl, hxr, hatt + j * 512, hbias + j * 128,
        hg + j * 128, hbeta + j * 128, Hf, Hf_bf,
        j == 1 ? HfRes : nullptr, j == 0 ? 1 : 0);
  }

  float* x = (float*)d_out;
  unpool_k<<<NTOT, 64, 0, stream>>>(s, Hf, hh, x, x_bf);
  gemm_bf16<<<dim3(NTOT / 128, 4), 256, 0, stream>>>(x_bf, W1T, mlp_b1, mlp_b1,
      nullptr, t_bf, nullptr, nullptr, NTOT, 128, 512, 512, 1, 0);
  gemm64_bf16<<<dim3(NTOT / 64, 1), 256, 0, stream>>>(t_bf, W2T, mlp_b2, mlp_b2,
      x, nullptr, nullptr, x, NTOT, 512, 128, 128, 0);
}

// Round 13
// 380.200 us; speedup vs baseline: 1.0375x; 1.0375x over previous
//
#include <hip/hip_runtime.h>
#include <math.h>

#define NTOT  16384
#define NNODE 1024

typedef unsigned short u16;
typedef unsigned short u16x8 __attribute__((ext_vector_type(8)));
typedef short s16x8 __attribute__((ext_vector_type(8)));
typedef float f32x4 __attribute__((ext_vector_type(4)));

static __device__ __forceinline__ float b2f(u16 u) {
  return __uint_as_float(((unsigned)u) << 16);
}
static __device__ __forceinline__ u16 f2b(float f) {
  unsigned x = __float_as_uint(f);
  return (u16)((x + 0x7FFFu + ((x >> 16) & 1u)) >> 16);
}

// async global->LDS, 16B per lane; LDS dest = wave-uniform base + lane*16
typedef __attribute__((address_space(1))) const void gvoid;
typedef __attribute__((address_space(3))) void lvoid;
static __device__ __forceinline__ void gload16(const void* g, void* lds) {
  __builtin_amdgcn_global_load_lds((gvoid*)g, (lvoid*)lds, 16, 0, 0);
}

// ---------------- embedding: h = obs @ Wemb + b (K=32, N=128) ----------------
__global__ __launch_bounds__(64) void emb_k(const float* __restrict__ obs,
    const float* __restrict__ W, const float* __restrict__ b,
    float* __restrict__ h, float* __restrict__ hh, u16* __restrict__ h_bf)
{
  int n = blockIdx.x, l = threadIdx.x;
  __shared__ float ob[32];
  if (l < 32) ob[l] = obs[n * 32 + l];
  __syncthreads();
  float a0 = b[l], a1 = b[64 + l];
  #pragma unroll
  for (int k = 0; k < 32; ++k) {
    float o = ob[k];
    a0 = fmaf(o, W[k * 128 + l], a0);
    a1 = fmaf(o, W[k * 128 + 64 + l], a1);
  }
  size_t base = (size_t)n * 128;
  h[base + l] = a0;  h[base + 64 + l] = a1;
  hh[base + l] = a0; hh[base + 64 + l] = a1;
  h_bf[base + l] = f2b(a0); h_bf[base + 64 + l] = f2b(a1);
}

// ---------------- CSR build ----------------
__global__ void hist_k(const int* __restrict__ ei, int E0, int* __restrict__ deg)
{
  int i = blockIdx.x * blockDim.x + threadIdx.x;
  int ET = E0 + NTOT;
  if (i < ET) {
    int d = (i < E0) ? ei[E0 + i] : (i - E0);
    atomicAdd(&deg[d], 1);
  }
}

__global__ __launch_bounds__(256) void scan_k(const int* __restrict__ deg,
    int* __restrict__ off, int* __restrict__ cursor)
{
  int t = threadIdx.x, lane = t & 63, wid = t >> 6;
  int base = t * 64;
  int sum = 0;
  for (int i = 0; i < 64; ++i) sum += deg[base + i];
  int inc = sum;
  #pragma unroll
  for (int d = 1; d < 64; d <<= 1) {
    int u = __shfl_up(inc, d);
    if (lane >= d) inc += u;
  }
  __shared__ int wt[4];
  if (lane == 63) wt[wid] = inc;
  __syncthreads();
  int woff = 0;
  for (int i = 0; i < wid; ++i) woff += wt[i];
  int run = woff + inc - sum;      // exclusive prefix of this thread's 64-chunk
  for (int i = 0; i < 64; ++i) {
    off[base + i] = run; cursor[base + i] = run;
    run += deg[base + i];
  }
  if (t == 255) off[NTOT] = run;
}

__global__ void scat_k(const int* __restrict__ ei, int E0,
    int* __restrict__ cursor, int* __restrict__ csr_src)
{
  int i = blockIdx.x * blockDim.x + threadIdx.x;
  int ET = E0 + NTOT;
  if (i < ET) {
    int s, d;
    if (i < E0) { s = ei[i]; d = ei[E0 + i]; } else { s = d = i - E0; }
    int pos = atomicAdd(&cursor[d], 1);
    csr_src[pos] = s;
  }
}

// ---------------- degree-sorted dst permutation (per graph, counting sort) --------
__global__ void dhist_k(const int* __restrict__ deg, int* __restrict__ dh)
{
  int n = blockIdx.x * 256 + threadIdx.x;
  if (n < NTOT) {
    int d = deg[n]; d = d < 63 ? d : 63;
    atomicAdd(&dh[(n >> 10) * 64 + d], 1);
  }
}
__global__ void dscan_k(const int* __restrict__ dh, int* __restrict__ dcur)
{
  int g = threadIdx.x;
  if (g < 16) {
    int run = 0;
    for (int d = 0; d < 64; ++d) { dcur[g * 64 + d] = run; run += dh[g * 64 + d]; }
  }
}
__global__ void dscat_k(const int* __restrict__ deg, int* __restrict__ dcur,
                        int* __restrict__ perm)
{
  int n = blockIdx.x * 256 + threadIdx.x;
  if (n < NTOT) {
    int gph = n >> 10;
    int d = deg[n]; d = d < 63 ? d : 63;
    int pos = atomicAdd(&dcur[gph * 64 + d], 1);
    perm[gph * 1024 + pos] = n;
  }
}

// ---------------- all weight transposes + bf16 quantize in ONE kernel ----------------
// out layout: [lWT 262144][hWT 262144][W1T 65536][W2T 65536]
__global__ void wqall_k(const float* __restrict__ lWl, const float* __restrict__ lWr,
                        const float* __restrict__ hWl, const float* __restrict__ hWr,
                        const float* __restrict__ W1, const float* __restrict__ W2,
                        u16* __restrict__ out)
{
  int idx = blockIdx.x * 256 + threadIdx.x;
  if (idx >= 655360) return;
  float v;
  if (idx < 524288) {
    const float* Wl = idx < 262144 ? lWl : hWl;
    const float* Wr = idx < 262144 ? lWr : hWr;
    int r2 = idx & 262143;
    int m = r2 >> 17, r = r2 & 131071;
    int n = r >> 7, k = r & 127;
    const float* W = (n < 512) ? Wl : Wr;
    v = W[(size_t)m * 65536 + (size_t)k * 512 + (n & 511)];
  } else if (idx < 589824) {
    int i = idx - 524288;
    int n = i >> 7, k = i & 127;
    v = W1[k * 512 + n];
  } else {
    int i = idx - 589824;
    int n = i >> 9, k = i & 511;
    v = W2[k * 128 + n];
  }
  out[idx] = f2b(v);
}

// ---------------- bf16 MFMA GEMM (BM=128): C = A[M,K] @ Bt[N,K]^T + bias ----------------
__global__ __launch_bounds__(256) void gemm_bf16(
    const u16* __restrict__ A, const u16* __restrict__ Bt,
    const float* __restrict__ bias0, const float* __restrict__ bias1,
    float* __restrict__ Cf, u16* __restrict__ Cb0, u16* __restrict__ Cb1,
    const float* __restrict__ res,
    int M, int K, int N, int Nsplit, int act, int rswz)
{
  __shared__ u16 Al[128][128];
  __shared__ u16 Bl[128][128];
  const int tid = threadIdx.x;
  int bx = blockIdx.x;
  if (rswz) bx = (bx & 7) * 16 + (bx >> 3);
  const int bm = bx * 128, bn = blockIdx.y * 128;
  const int w = tid >> 6, l = tid & 63;
  const int fr = l & 15;
  const int kg = l >> 4;
  const int lrow = l >> 4, gsl = l & 15;

  f32x4 acc[2][8];
  #pragma unroll
  for (int a = 0; a < 2; ++a)
    #pragma unroll
    for (int b = 0; b < 8; ++b)
      acc[a][b] = (f32x4){0.f, 0.f, 0.f, 0.f};

  for (int k0 = 0; k0 < K; k0 += 128) {
    __syncthreads();
    #pragma unroll
    for (int j = 0; j < 8; ++j) {
      int row = w * 32 + j * 4 + lrow;
      int gsrc = gsl ^ (row & 7);
      gload16(A + (size_t)(bm + row) * K + k0 + gsrc * 8, &Al[w * 32 + j * 4][0]);
    }
    #pragma unroll
    for (int j = 0; j < 8; ++j) {
      int row = w * 32 + j * 4 + lrow;
      int gsrc = gsl ^ (row & 7);
      gload16(Bt + (size_t)(bn + row) * K + k0 + gsrc * 8, &Bl[w * 32 + j * 4][0]);
    }
    __syncthreads();
    #pragma unroll
    for (int ks = 0; ks < 4; ++ks) {
      const int g = (ks << 2) + kg;
      const int ar0 = w * 32 + fr, ar1 = ar0 + 16;
      s16x8 a0 = *(const s16x8*)&Al[ar0][(g ^ (ar0 & 7)) << 3];
      s16x8 a1 = *(const s16x8*)&Al[ar1][(g ^ (ar1 & 7)) << 3];
      #pragma unroll
      for (int nr = 0; nr < 8; ++nr) {
        const int br = nr * 16 + fr;
        s16x8 bb = *(const s16x8*)&Bl[br][(g ^ (br & 7)) << 3];
        acc[0][nr] = __builtin_amdgcn_mfma_f32_16x16x32_bf16(a0, bb, acc[0][nr], 0, 0, 0);
        acc[1][nr] = __builtin_amdgcn_mfma_f32_16x16x32_bf16(a1, bb, acc[1][nr], 0, 0, 0);
      }
    }
  }

  #pragma unroll
  for (int mr = 0; mr < 2; ++mr) {
    const int row0 = bm + w * 32 + mr * 16 + (kg << 2);
    #pragma unroll
    for (int nr = 0; nr < 8; ++nr) {
      const int col = bn + nr * 16 + fr;
      const int half = (col >= Nsplit);
      const int c2 = half ? col - Nsplit : col;
      const int str = half ? (N - Nsplit) : Nsplit;
      const float bb = half ? bias1[c2] : bias0[c2];
      u16* cb = half ? Cb1 : Cb0;
      #pragma unroll
      for (int j = 0; j < 4; ++j) {
        float v = acc[mr][nr][j] + bb;
        if (act) v = tanhf(v);
        size_t o = (size_t)(row0 + j) * str + c2;
        if (res) v += res[o];
        if (Cf) Cf[o] = v;
        if (cb) cb[o] = f2b(v);
      }
    }
  }
}

// ---------------- bf16 MFMA GEMM (BM=64) — for skinny/tall shapes ----------------
__global__ __launch_bounds__(256) void gemm64_bf16(
    const u16* __restrict__ A, const u16* __restrict__ Bt,
    const float* __restrict__ bias0, const float* __restrict__ bias1,
    float* __restrict__ Cf, u16* __restrict__ Cb0, u16* __restrict__ Cb1,
    const float* __restrict__ res,
    int M, int K, int N, int Nsplit, int act)
{
  __shared__ u16 Al[64][128];
  __shared__ u16 Bl[128][128];
  const int tid = threadIdx.x;
  const int bm = blockIdx.x * 64, bn = blockIdx.y * 128;
  const int w = tid >> 6, l = tid & 63;
  const int fr = l & 15;
  const int kg = l >> 4;
  const int lrow = l >> 4, gsl = l & 15;

  f32x4 acc[8];
  #pragma unroll
  for (int b = 0; b < 8; ++b) acc[b] = (f32x4){0.f, 0.f, 0.f, 0.f};

  for (int k0 = 0; k0 < K; k0 += 128) {
    __syncthreads();
    #pragma unroll
    for (int j = 0; j < 4; ++j) {
      int row = w * 16 + j * 4 + lrow;
      int gsrc = gsl ^ (row & 7);
      gload16(A + (size_t)(bm + row) * K + k0 + gsrc * 8, &Al[w * 16 + j * 4][0]);
    }
    #pragma unroll
    for (int j = 0; j < 8; ++j) {
      int row = w * 32 + j * 4 + lrow;
      int gsrc = gsl ^ (row & 7);
      gload16(Bt + (size_t)(bn + row) * K + k0 + gsrc * 8, &Bl[w * 32 + j * 4][0]);
    }
    __syncthreads();
    #pragma unroll
    for (int ks = 0; ks < 4; ++ks) {
      const int g = (ks << 2) + kg;
      const int ar0 = w * 16 + fr;
      s16x8 a0 = *(const s16x8*)&Al[ar0][(g ^ (ar0 & 7)) << 3];
      #pragma unroll
      for (int nr = 0; nr < 8; ++nr) {
        const int br = nr * 16 + fr;
        s16x8 bb = *(const s16x8*)&Bl[br][(g ^ (br & 7)) << 3];
        acc[nr] = __builtin_amdgcn_mfma_f32_16x16x32_bf16(a0, bb, acc[nr], 0, 0, 0);
      }
    }
  }

  const int row0 = bm + w * 16 + (kg << 2);
  #pragma unroll
  for (int nr = 0; nr < 8; ++nr) {
    const int col = bn + nr * 16 + fr;
    const int half = (col >= Nsplit);
    const int c2 = half ? col - Nsplit : col;
    const int str = half ? (N - Nsplit) : Nsplit;
    const float bb = half ? bias1[c2] : bias0[c2];
    u16* cb = half ? Cb1 : Cb0;
    #pragma unroll
    for (int j = 0; j < 4; ++j) {
      float v = acc[nr][j] + bb;
      if (act) v = tanhf(v);
      size_t o = (size_t)(row0 + j) * str + c2;
      if (res) v += res[o];
      if (Cf) Cf[o] = v;
      if (cb) cb[o] = f2b(v);
    }
  }
}

// ---------------- GATv2 edge step (online softmax, one head per 16-lane group)
static __device__ __forceinline__ void estep(
    u16x8 vv, bool valid, u16x8 xrb, const float* attr,
    float& m, float& z, float* acc)
{
  float xv[8], part = 0.f;
  #pragma unroll
  for (int i = 0; i < 8; ++i) {
    xv[i] = b2f(vv[i]);
    float v = xv[i] + b2f(xrb[i]);
    part = fmaf(fmaxf(v, 0.2f * v), attr[i], part);   // leaky_relu
  }
  part += __shfl_xor(part, 1); part += __shfl_xor(part, 2);
  part += __shfl_xor(part, 4); part += __shfl_xor(part, 8);
  if (!valid) part = -1e30f;
  float mn = fmaxf(m, part);
  float sc = __expf(m - mn);
  float p  = __expf(part - mn);
  z = z * sc + p;
  #pragma unroll
  for (int i = 0; i < 8; ++i) acc[i] = fmaf(acc[i], sc, p * xv[i]);
  m = mn;
}

// ---------------- dual-dst fused GATv2, symmetric two-pair scheduling ----------
// 4096 waves; wave jw of graph g processes sorted pair jw AND pair 511-jw ->
// per-wave total work ~ 2x median degree (balanced makespan, no idle tail)
__global__ __launch_bounds__(256) void gat_agg2(
    const u16* __restrict__ xl, const u16* __restrict__ xr,
    const int* __restrict__ off, const int* __restrict__ srcs,
    const int* __restrict__ perm,
    const float* __restrict__ att, const float* __restrict__ bias,
    const float* __restrict__ g, const float* __restrict__ beta,
    float* __restrict__ h, u16* __restrict__ h_bf,
    const float* __restrict__ res2, int do_silu, int swz)
{
  const int b = blockIdx.x, tid = threadIdx.x;
  const int l = tid & 63, w = tid >> 6;
  int gph, jw;
  if (swz) {
    // pin graphs to XCDs: XCD x serves graphs {2x,2x+1} (matches gemm rswz)
    int xcd = b & 7, i = b >> 3;          // i: 0..127 (128 blocks/XCD)
    gph = (xcd << 1) + (i >> 6);
    jw = ((i & 63) << 2) + w;             // wave index within graph, 0..255
  } else {
    gph = b >> 6;
    jw = ((b & 63) << 2) + w;
  }

  float attr[8];
  {
    const float4 a0 = *(const float4*)(att + l * 8);
    const float4 a1 = *(const float4*)(att + l * 8 + 4);
    attr[0] = a0.x; attr[1] = a0.y; attr[2] = a0.z; attr[3] = a0.w;
    attr[4] = a1.x; attr[5] = a1.y; attr[6] = a1.z; attr[7] = a1.w;
  }
  const int d0 = (l & 15) * 8;

  #pragma unroll 1
  for (int pp = 0; pp < 2; ++pp) {
    const int bslot = (pp == 0) ? (jw << 1) : (1022 - (jw << 1));
    const int slot0 = gph * 1024 + bslot;
    const int dst0 = perm[slot0], dst1 = perm[slot0 + 1];

    u16x8 xrb0 = *(const u16x8*)(xr + (size_t)dst0 * 512 + l * 8);
    u16x8 xrb1 = *(const u16x8*)(xr + (size_t)dst1 * 512 + l * 8);

    const int s0 = off[dst0], n0 = off[dst0 + 1] - s0;
    const int s1 = off[dst1], n1 = off[dst1 + 1] - s1;
    const int nmax = n0 > n1 ? n0 : n1;   // degree-sorted: |n0-n1| ~ 0

    int ni0 = (n0 > 1) ? srcs[s0 + 1] : 0;
    int ni1 = (n1 > 1) ? srcs[s1 + 1] : 0;
    u16x8 v0 = *(const u16x8*)(xl + (size_t)srcs[s0] * 512 + l * 8);
    u16x8 v1 = *(const u16x8*)(xl + (size_t)srcs[s1] * 512 + l * 8);

    float m0 = -1e30f, z0 = 0.f, acc0[8] = {};
    float m1 = -1e30f, z1 = 0.f, acc1[8] = {};

    for (int e = 0; e < nmax; ++e) {
      u16x8 c0 = v0, c1 = v1;
      if (e + 1 < nmax) {
        v0 = *(const u16x8*)(xl + (size_t)ni0 * 512 + l * 8);
        v1 = *(const u16x8*)(xl + (size_t)ni1 * 512 + l * 8);
        if (e + 2 < n0) ni0 = srcs[s0 + e + 2];
        if (e + 2 < n1) ni1 = srcs[s1 + e + 2];
      }
      estep(c0, e < n0, xrb0, attr, m0, z0, acc0);
      estep(c1, e < n1, xrb1, attr, m1, z1, acc1);
    }

    float o0[8], o1[8];
    const float inv0 = 0.25f / z0, inv1 = 0.25f / z1; // mean over 4 heads folded
    #pragma unroll
    for (int i = 0; i < 8; ++i) {
      float v = acc0[i] * inv0;
      v += __shfl_xor(v, 16); v += __shfl_xor(v, 32); // sum heads
      o0[i] = v + bias[d0 + i];
      float w2 = acc1[i] * inv1;
      w2 += __shfl_xor(w2, 16); w2 += __shfl_xor(w2, 32);
      o1[i] = w2 + bias[d0 + i];
    }
    // LayerNorm over 128 dims (each 16-lane group holds a full copy)
    float sa = 0.f, sb = 0.f;
    #pragma unroll
    for (int i = 0; i < 8; ++i) { sa += o0[i]; sb += o1[i]; }
    sa += __shfl_xor(sa, 1); sa += __shfl_xor(sa, 2);
    sa += __shfl_xor(sa, 4); sa += __shfl_xor(sa, 8);
    sb += __shfl_xor(sb, 1); sb += __shfl_xor(sb, 2);
    sb += __shfl_xor(sb, 4); sb += __shfl_xor(sb, 8);
    const float mu0 = sa * (1.f / 128.f), mu1 = sb * (1.f / 128.f);
    float va = 0.f, vb = 0.f;
    #pragma unroll
    for (int i = 0; i < 8; ++i) {
      float d = o0[i] - mu0; va += d * d;
      float e = o1[i] - mu1; vb += e * e;
    }
    va += __shfl_xor(va, 1); va += __shfl_xor(va, 2);
    va += __shfl_xor(va, 4); va += __shfl_xor(va, 8);
    vb += __shfl_xor(vb, 1); vb += __shfl_xor(vb, 2);
    vb += __shfl_xor(vb, 4); vb += __shfl_xor(vb, 8);
    const float rstd0 = rsqrtf(va * (1.f / 128.f) + 1e-5f);
    const float rstd1 = rsqrtf(vb * (1.f / 128.f) + 1e-5f);

    const float* oo = (l < 16) ? o0 : o1;
    const float mu = (l < 16) ? mu0 : mu1;
    const float rstd = (l < 16) ? rstd0 : rstd1;
    const int dd = (l < 16) ? dst0 : dst1;
    if (l < 32) {
      size_t base = (size_t)dd * 128 + d0;
      float4 r0 = *(const float4*)(h + base);
      float4 r1 = *(const float4*)(h + base + 4);
      float rr[8] = {r0.x, r0.y, r0.z, r0.w, r1.x, r1.y, r1.z, r1.w};
      if (res2) {
        float4 q0 = *(const float4*)(res2 + base);
        float4 q1 = *(const float4*)(res2 + base + 4);
        rr[0] += q0.x; rr[1] += q0.y; rr[2] += q0.z; rr[3] += q0.w;
        rr[4] += q1.x; rr[5] += q1.y; rr[6] += q1.z; rr[7] += q1.w;
      }
      float out[8];
      u16x8 hb;
      #pragma unroll
      for (int i = 0; i < 8; ++i) {
        float y = (oo[i] - mu) * rstd * g[d0 + i] + beta[d0 + i];
        if (do_silu) y = y / (1.f + __expf(-y));
        out[i] = y + rr[i];
        hb[i] = f2b(out[i]);
      }
      *(float4*)(h + base) = make_float4(out[0], out[1], out[2], out[3]);
      *(float4*)(h + base + 4) = make_float4(out[4], out[5], out[6], out[7]);
      *(u16x8*)(h_bf + base) = hb;
    }
  }
}

// ---------------- fully-connected-16 GATv2 (high level): shared row loads ----------------
__global__ __launch_bounds__(64) void gat_fc16(
    const u16* __restrict__ xl, const u16* __restrict__ xr,
    const float* __restrict__ att, const float* __restrict__ bias,
    const float* __restrict__ g, const float* __restrict__ beta,
    float* __restrict__ h, u16* __restrict__ h_bf,
    const float* __restrict__ res2, int do_silu)
{
  int b = blockIdx.x, l = threadIdx.x;
  const int dst0 = b << 2;
  const int gbase = dst0 & ~15;      // all 4 dsts share one 16-node graph

  float attr[8];
  {
    const float4 a0 = *(const float4*)(att + l * 8);
    const float4 a1 = *(const float4*)(att + l * 8 + 4);
    attr[0] = a0.x; attr[1] = a0.y; attr[2] = a0.z; attr[3] = a0.w;
    attr[4] = a1.x; attr[5] = a1.y; attr[6] = a1.z; attr[7] = a1.w;
  }
  u16x8 xrb[4];
  #pragma unroll
  for (int q = 0; q < 4; ++q)
    xrb[q] = *(const u16x8*)(xr + (size_t)(dst0 + q) * 512 + l * 8);

  float m[4] = {-1e30f, -1e30f, -1e30f, -1e30f};
  float z[4] = {0.f, 0.f, 0.f, 0.f};
  float acc[4][8] = {};
  u16x8 vcur = *(const u16x8*)(xl + (size_t)gbase * 512 + l * 8);
  for (int e = 0; e < 16; ++e) {
    u16x8 c = vcur;
    if (e < 15) vcur = *(const u16x8*)(xl + (size_t)(gbase + e + 1) * 512 + l * 8);
    estep(c, true, xrb[0], attr, m[0], z[0], acc[0]);
    estep(c, true, xrb[1], attr, m[1], z[1], acc[1]);
    estep(c, true, xrb[2], attr, m[2], z[2], acc[2]);
    estep(c, true, xrb[3], attr, m[3], z[3], acc[3]);
  }

  const int d0 = (l & 15) * 8;
  float mu[4], rs[4];
  #pragma unroll
  for (int q = 0; q < 4; ++q) {
    const float inv = 0.25f / z[q];
    #pragma unroll
    for (int i = 0; i < 8; ++i) {
      float x = acc[q][i] * inv;
      x += __shfl_xor(x, 16); x += __shfl_xor(x, 32);
      acc[q][i] = x + bias[d0 + i];
    }
    float sa = 0.f;
    #pragma unroll
    for (int i = 0; i < 8; ++i) sa += acc[q][i];
    sa += __shfl_xor(sa, 1); sa += __shfl_xor(sa, 2);
    sa += __shfl_xor(sa, 4); sa += __shfl_xor(sa, 8);
    mu[q] = sa * (1.f / 128.f);
    float va = 0.f;
    #pragma unroll
    for (int i = 0; i < 8; ++i) { float d = acc[q][i] - mu[q]; va += d * d; }
    va += __shfl_xor(va, 1); va += __shfl_xor(va, 2);
    va += __shfl_xor(va, 4); va += __shfl_xor(va, 8);
    rs[q] = rsqrtf(va * (1.f / 128.f) + 1e-5f);
  }
  float oo[8];
  #pragma unroll
  for (int i = 0; i < 8; ++i)
    oo[i] = (l < 32) ? (l < 16 ? acc[0][i] : acc[1][i])
                     : (l < 48 ? acc[2][i] : acc[3][i]);
  const float mmu = (l < 32) ? (l < 16 ? mu[0] : mu[1]) : (l < 48 ? mu[2] : mu[3]);
  const float mrs = (l < 32) ? (l < 16 ? rs[0] : rs[1]) : (l < 48 ? rs[2] : rs[3]);
  const int dd = dst0 + (l >> 4);
  size_t base = (size_t)dd * 128 + d0;
  float4 r0 = *(const float4*)(h + base);
  float4 r1 = *(const float4*)(h + base + 4);
  float rr[8] = {r0.x, r0.y, r0.z, r0.w, r1.x, r1.y, r1.z, r1.w};
  if (res2) {
    float4 q0 = *(const float4*)(res2 + base);
    float4 q1 = *(const float4*)(res2 + base + 4);
    rr[0] += q0.x; rr[1] += q0.y; rr[2] += q0.z; rr[3] += q0.w;
    rr[4] += q1.x; rr[5] += q1.y; rr[6] += q1.z; rr[7] += q1.w;
  }
  float out[8];
  u16x8 hb;
  #pragma unroll
  for (int i = 0; i < 8; ++i) {
    float y = (oo[i] - mmu) * mrs * g[d0 + i] + beta[d0 + i];
    if (do_silu) y = y / (1.f + __expf(-y));
    out[i] = y + rr[i];
    hb[i] = f2b(out[i]);
  }
  *(float4*)(h + base) = make_float4(out[0], out[1], out[2], out[3]);
  *(float4*)(h + base + 4) = make_float4(out[4], out[5], out[6], out[7]);
  *(u16x8*)(h_bf + base) = hb;
}

// ---------------- fused pooling softmax + cluster partials ----------------
#define HF_CHUNK 32
#define HF_NCH   32
__global__ __launch_bounds__(256) void poolhf_k(const float* __restrict__ h,
    const float* __restrict__ pW, const float* __restrict__ pb,
    float* __restrict__ s, float* __restrict__ part, float* __restrict__ cpart)
{
  __shared__ float hs[HF_CHUNK][128];   // 16 KB
  __shared__ float Ws[128][16];         // 8 KB
  __shared__ float ss[HF_CHUNK][16];    // 2 KB
  int b = blockIdx.x >> 5, chunk = blockIdx.x & 31;
  int n0 = b * NNODE + chunk * HF_CHUNK;
  int t = threadIdx.x;
  #pragma unroll
  for (int i = 0; i < 4; ++i) {
    int idx = t + 256 * i;              // float4 index 0..1023
    int row = idx >> 5, c4 = (idx & 31) * 4;
    *(float4*)&hs[row][c4] = *(const float4*)(h + (size_t)(n0 + row) * 128 + c4);
  }
  #pragma unroll
  for (int i = 0; i < 2; ++i) {
    int idx = t + 256 * i;              // float4 index 0..511
    *(float4*)&Ws[idx >> 2][(idx & 3) * 4] = *(const float4*)(pW + idx * 4);
  }
  __syncthreads();
  // pooling softmax: thread t -> nodes {t>>4, 16+(t>>4)}, class c = t&15
  const int c = t & 15, nA = t >> 4;
  const float bb = pb[c];
  #pragma unroll
  for (int half = 0; half < 2; ++half) {
    const int nn = nA + half * 16;
    float a = bb;
    for (int k = 0; k < 128; ++k) a = fmaf(hs[nn][k], Ws[k][c], a);
    float mx = a;
    mx = fmaxf(mx, __shfl_xor(mx, 1)); mx = fmaxf(mx, __shfl_xor(mx, 2));
    mx = fmaxf(mx, __shfl_xor(mx, 4)); mx = fmaxf(mx, __shfl_xor(mx, 8));
    float p = __expf(a - mx), sum = p;
    sum += __shfl_xor(sum, 1); sum += __shfl_xor(sum, 2);
    sum += __shfl_xor(sum, 4); sum += __shfl_xor(sum, 8);
    float sv = p / sum;
    ss[nn][c] = sv;
    s[(size_t)(n0 + nn) * 16 + c] = sv;
  }
  __syncthreads();
  // partials: thread t -> dim d = t&127, classes cg..cg+7
  const int d = t & 127, cg = (t >> 7) * 8;
  float acc[8] = {};
  for (int n = 0; n < HF_CHUNK; ++n) {
    float hv = hs[n][d];
    #pragma unroll
    for (int i = 0; i < 8; ++i) acc[i] = fmaf(ss[n][cg + i], hv, acc[i]);
  }
  float* po = part + (size_t)chunk * 32768 + (size_t)(b * 16 + cg) * 128 + d;
  #pragma unroll
  for (int i = 0; i < 8; ++i) po[i * 128] = acc[i];
  if (t < 16) {
    float cs = 0.f;
    #pragma unroll
    for (int n = 0; n < HF_CHUNK; ++n) cs += ss[n][t];
    cpart[chunk * 256 + b * 16 + t] = cs;
  }
}

// ---------------- cluster features, stage 2: reduce chunks + normalize
__global__ __launch_bounds__(256) void hfr_k(const float* __restrict__ part,
    const float* __restrict__ cpart, float* __restrict__ Hf,
    float* __restrict__ HfRes, u16* __restrict__ Hf_bf)
{
  int o = blockIdx.x * 256 + threadIdx.x;
  int bc = o >> 7;
  float a = 0.f, cnt = 0.f;
  #pragma unroll 8
  for (int ch = 0; ch < HF_NCH; ++ch) {
    a += part[(size_t)ch * 32768 + o];
    cnt += cpart[ch * 256 + bc];
  }
  float v = a / fmaxf(cnt, 1e-5f);
  Hf[o] = v; HfRes[o] = v; Hf_bf[o] = f2b(v);
}

// ---------------- unpool + residual: x = s @ Hf + hh ----------------
__global__ __launch_bounds__(64) void unpool_k(const float* __restrict__ s,
    const float* __restrict__ Hf, const float* __restrict__ hh,
    float* __restrict__ x, u16* __restrict__ x_bf)
{
  int n = blockIdx.x, l = threadIdx.x;
  int b = n >> 10;
  float a0 = 0.f, a1 = 0.f;
  #pragma unroll
  for (int c = 0; c < 16; ++c) {
    float sv = s[(size_t)n * 16 + c];
    const float* hp = Hf + (size_t)((b << 4) + c) * 128;
    a0 = fmaf(sv, hp[l], a0);
    a1 = fmaf(sv, hp[64 + l], a1);
  }
  size_t base = (size_t)n * 128;
  float v0 = a0 + hh[base + l], v1 = a1 + hh[base + 64 + l];
  x[base + l] = v0; x[base + 64 + l] = v1;
  x_bf[base + l] = f2b(v0); x_bf[base + 64 + l] = f2b(v1);
}

extern "C" void kernel_launch(void* const* d_in, const int* in_sizes, int n_in,
                              void* d_out, int out_size, void* d_ws, size_t ws_size,
                              hipStream_t stream) {
  (void)n_in; (void)out_size; (void)ws_size;
  const float* obs    = (const float*)d_in[0];
  const int*   ei     = (const int*)d_in[1];
  const float* emb_W  = (const float*)d_in[3];
  const float* emb_b  = (const float*)d_in[4];
  const float* pool_W = (const float*)d_in[5];
  const float* pool_b = (const float*)d_in[6];
  const float* mlp_W1 = (const float*)d_in[7];
  const float* mlp_b1 = (const float*)d_in[8];
  const float* mlp_W2 = (const float*)d_in[9];
  const float* mlp_b2 = (const float*)d_in[10];
  const float* lWl = (const float*)d_in[11]; const float* lbl = (const float*)d_in[12];
  const float* lWr = (const float*)d_in[13]; const float* lbr = (const float*)d_in[14];
  const float* latt = (const float*)d_in[15]; const float* lbias = (const float*)d_in[16];
  const float* lg = (const float*)d_in[17]; const float* lbeta = (const float*)d_in[18];
  const float* hWl = (const float*)d_in[19]; const float* hbl = (const float*)d_in[20];
  const float* hWr = (const float*)d_in[21]; const float* hbr = (const float*)d_in[22];
  const float* hatt = (const float*)d_in[23]; const float* hbias = (const float*)d_in[24];
  const float* hg = (const float*)d_in[25]; const float* hbeta = (const float*)d_in[26];

  const int E0 = in_sizes[1] / 2;
  const int ET = E0 + NTOT;

  char* p = (char*)d_ws;
  auto alloc = [&](size_t bytes) -> void* {
    void* q = (void*)p;
    p += (bytes + 255) & ~(size_t)255;
    return q;
  };
  float* h      = (float*)alloc((size_t)NTOT * 128 * 4);
  float* hh     = (float*)alloc((size_t)NTOT * 128 * 4);
  u16*   h_bf   = (u16*)alloc((size_t)NTOT * 128 * 2);
  u16*   xl_bf  = (u16*)alloc((size_t)NTOT * 512 * 2);
  u16*   xr_bf  = (u16*)alloc((size_t)NTOT * 512 * 2);
  u16*   x_bf   = (u16*)alloc((size_t)NTOT * 128 * 2);
  float* s      = (float*)alloc((size_t)NTOT * 16 * 4);
  float* Hf     = (float*)alloc(256 * 128 * 4);
  float* HfRes  = (float*)alloc(256 * 128 * 4);
  u16*   Hf_bf  = (u16*)alloc(256 * 128 * 2);
  u16*   hxl    = (u16*)alloc(256 * 512 * 2);
  u16*   hxr    = (u16*)alloc(256 * 512 * 2);
  float* hfPart = (float*)alloc((size_t)HF_NCH * 32768 * 4);
  float* hfCnt  = (float*)alloc((size_t)HF_NCH * 256 * 4);
  u16*   WT     = (u16*)alloc((size_t)655360 * 2);   // [lWT|hWT|W1T|W2T]
  int* deg      = (int*)alloc((size_t)NTOT * 4);
  int* off      = (int*)alloc((size_t)(NTOT + 1) * 4);
  int* cursor   = (int*)alloc((size_t)NTOT * 4);
  int* csr      = (int*)alloc((size_t)ET * 4);
  int* perm     = (int*)alloc((size_t)NTOT * 4);
  int* dh       = (int*)alloc(16 * 64 * 4);
  int* dcur     = (int*)alloc(16 * 64 * 4);
  u16* lWT = WT;
  u16* hWT = WT + 262144;
  u16* W1T = WT + 524288;
  u16* W2T = WT + 589824;
  u16* t_bf = xl_bf;   // alias: xl_bf is free by MLP time

  wqall_k<<<2560, 256, 0, stream>>>(lWl, lWr, hWl, hWr, mlp_W1, mlp_W2, WT);

  hipMemsetAsync(deg, 0, (size_t)NTOT * 4, stream);
  hipMemsetAsync(dh, 0, 16 * 64 * 4, stream);
  emb_k<<<NTOT, 64, 0, stream>>>(obs, emb_W, emb_b, h, hh, h_bf);
  hist_k<<<(ET + 255) / 256, 256, 0, stream>>>(ei, E0, deg);
  scan_k<<<1, 256, 0, stream>>>(deg, off, cursor);
  scat_k<<<(ET + 255) / 256, 256, 0, stream>>>(ei, E0, cursor, csr);
  dhist_k<<<NTOT / 256, 256, 0, stream>>>(deg, dh);
  dscan_k<<<1, 64, 0, stream>>>(dh, dcur);
  dscat_k<<<NTOT / 256, 256, 0, stream>>>(deg, dcur, perm);

  // low-level GAT stack (in-place on h; stack residual == hh)
  for (int j = 0; j < 2; ++j) {
    gemm_bf16<<<dim3(NTOT / 128, 8), 256, 0, stream>>>(h_bf, lWT + j * 131072,
        lbl + j * 512, lbr + j * 512, nullptr, xl_bf, xr_bf, nullptr,
        NTOT, 128, 1024, 512, 0, 1);
    gat_agg2<<<NTOT / 16, 256, 0, stream>>>(xl_bf, xr_bf, off, csr, perm,
        latt + j * 512, lbias + j * 128, lg + j * 128, lbeta + j * 128, h, h_bf,
        j == 1 ? hh : nullptr, j == 0 ? 1 : 0, 1);
  }

  poolhf_k<<<16 * HF_NCH, 256, 0, stream>>>(h, pool_W, pool_b, s, hfPart, hfCnt);
  hfr_k<<<128, 256, 0, stream>>>(hfPart, hfCnt, Hf, HfRes, Hf_bf);

  // high-level GAT stack on 256 cluster nodes (fully-connected 16-node graphs)
  for (int j = 0; j < 2; ++j) {
    gemm64_bf16<<<dim3(4, 8), 256, 0, stream>>>(Hf_bf, hWT + j * 131072,
        hbl + j * 512, hbr + j * 512, nullptr, hxl, hxr, nullptr,
        256, 128, 1024, 512, 0);
    gat_fc16<<<64, 64, 0, stream>>>(hxl, hxr, hatt + j * 512, hbias + j * 128,
        hg + j * 128, hbeta + j * 128, Hf, Hf_bf,
        j == 1 ? HfRes : nullptr, j == 0 ? 1 : 0);
  }

  float* x = (float*)d_out;
  unpool_k<<<NTOT, 64, 0, stream>>>(s, Hf, hh, x, x_bf);
  gemm_bf16<<<dim3(NTOT / 128, 4), 256, 0, stream>>>(x_bf, W1T, mlp_b1, mlp_b1,
      nullptr, t_bf, nullptr, nullptr, NTOT, 128, 512, 512, 1, 0);
  gemm64_bf16<<<dim3(NTOT / 64, 1), 256, 0, stream>>>(t_bf, W2T, mlp_b2, mlp_b2,
      x, nullptr, nullptr, x, NTOT, 512, 128, 128, 0);
}